// Round 9
// baseline (548.295 us; speedup 1.0000x reference)
//
#include <hip/hip_runtime.h>
#include <math.h>

#define Bsz 128
#define Hh 14
#define Ww 14
#define Nn 196
#define Cc 768
#define Gg 8
#define CgC 96
#define NHh 12
#define Dh 64
#define ROWS (Bsz*Nn)   // 25088

typedef _Float16 half8 __attribute__((ext_vector_type(8)));
typedef _Float16 half4 __attribute__((ext_vector_type(4)));
typedef float f32x4 __attribute__((ext_vector_type(4)));

// ---------------------------------------------------------------------------
// fp32 -> fp16 converters (one-shot, memory-bound)
// ---------------------------------------------------------------------------
__global__ __launch_bounds__(256) void cvt_f32_f16(
    const float* __restrict__ src, _Float16* __restrict__ dst, int n8)
{
  const int i = blockIdx.x * 256 + threadIdx.x;
  if (i >= n8) return;
  float4 a = *(const float4*)(src + (size_t)i * 8);
  float4 b = *(const float4*)(src + (size_t)i * 8 + 4);
  half8 h;
  h[0]=(_Float16)a.x; h[1]=(_Float16)a.y; h[2]=(_Float16)a.z; h[3]=(_Float16)a.w;
  h[4]=(_Float16)b.x; h[5]=(_Float16)b.y; h[6]=(_Float16)b.z; h[7]=(_Float16)b.w;
  *(half8*)(dst + (size_t)i * 8) = h;
}

__global__ __launch_bounds__(256) void cvt_w5(
    const float* __restrict__ w0, const float* __restrict__ w1,
    const float* __restrict__ w2, const float* __restrict__ w3,
    const float* __restrict__ w4, _Float16* __restrict__ dst)
{
  const int i = blockIdx.x * 256 + threadIdx.x;   // per 8 elems
  const int per = Cc * Cc / 8;                    // 73728
  if (i >= 5 * per) return;
  const int m = i / per, r = i - m * per;
  const float* s = (m == 0) ? w0 : (m == 1) ? w1 : (m == 2) ? w2 : (m == 3) ? w3 : w4;
  float4 a = *(const float4*)(s + (size_t)r * 8);
  float4 b = *(const float4*)(s + (size_t)r * 8 + 4);
  half8 h;
  h[0]=(_Float16)a.x; h[1]=(_Float16)a.y; h[2]=(_Float16)a.z; h[3]=(_Float16)a.w;
  h[4]=(_Float16)b.x; h[5]=(_Float16)b.y; h[6]=(_Float16)b.z; h[7]=(_Float16)b.w;
  *(half8*)(dst + (size_t)m * Cc * Cc + (size_t)r * 8) = h;
}

// ---------------------------------------------------------------------------
// b' = Wo @ bproj + bout  (fp32, tiny)
// ---------------------------------------------------------------------------
__global__ __launch_bounds__(256) void fuse_bias(
    const float* __restrict__ Wo, const float* __restrict__ bp,
    const float* __restrict__ bo, float* __restrict__ bf)
{
  const int o2 = blockIdx.x * 256 + threadIdx.x;
  if (o2 >= Cc) return;
  float s = bo[o2];
  const float* wrow = Wo + (size_t)o2 * Cc;
  for (int o = 0; o < Cc; ++o) s = fmaf(wrow[o], bp[o], s);
  bf[o2] = s;
}

// ---------------------------------------------------------------------------
// W' = Wo @ Wp  (768x768, fp16 in/out, fp32 accum). 36 blocks (6x6), BK=64.
// A = Wo rows (swizzled staging, as gemm_h16); B = Wp^T staged into a
// 72-padded transposed tile Bs[c][o]. Fragment k-maps identical to gemm_h16.
// ---------------------------------------------------------------------------
__global__ __launch_bounds__(256) void gemm_ww(
    const _Float16* __restrict__ Wo16, const _Float16* __restrict__ Wp16,
    _Float16* __restrict__ Wf)
{
  __shared__ __align__(16) _Float16 As[128 * 64];
  __shared__ __align__(16) _Float16 Bs[128 * 72];
  const int t = threadIdx.x;
  const int bid = blockIdx.x;
  const int colb = bid % 6, rowb = bid / 6;
  const int row0 = rowb * 128, col0 = colb * 128;
  const int lane = t & 63, w = t >> 6;
  const int wr = w >> 1, wc = w & 1;
  const int l15 = lane & 15, l4 = lane >> 4;
  const int srow = t >> 3;
  const int sg   = t & 7;

  f32x4 acc[4][4];
#pragma unroll
  for (int i = 0; i < 4; ++i)
#pragma unroll
    for (int j = 0; j < 4; ++j) acc[i][j] = (f32x4){0.f, 0.f, 0.f, 0.f};

  for (int kt = 0; kt < 12; ++kt) {
    const int k0 = kt * 64;
    // A staging (swizzled, same as gemm_h16)
#pragma unroll
    for (int it = 0; it < 4; ++it) {
      const int r = it * 32 + srow;
      half8 ha = *(const half8*)(Wo16 + (size_t)(row0 + r) * Cc + k0 + sg * 8);
      *(half8*)&As[r * 64 + ((sg ^ (r & 7)) * 8)] = ha;
    }
    // B staging transposed: Bs[c][o] = Wp[k0+o][col0+c]
    {
      const int og = t >> 4;          // 0..15 row group
      const int cg = t & 15;          // col granule (8 cols)
#pragma unroll
      for (int it = 0; it < 4; ++it) {
        const int o = it * 16 + og;   // 0..63
        half8 hv = *(const half8*)(Wp16 + (size_t)(k0 + o) * Cc + col0 + cg * 8);
#pragma unroll
        for (int e = 0; e < 8; ++e)
          Bs[(cg * 8 + e) * 72 + o] = hv[e];
      }
    }
    __syncthreads();
#pragma unroll
    for (int ks = 0; ks < 2; ++ks) {
      half8 af[4], bf[4];
#pragma unroll
      for (int mi = 0; mi < 4; ++mi) {
        const int r = wr * 64 + mi * 16 + l15;
        const int g = ks * 4 + l4;
        af[mi] = *(const half8*)&As[r * 64 + ((g ^ (r & 7)) * 8)];
      }
#pragma unroll
      for (int ni = 0; ni < 4; ++ni) {
        const int c = wc * 64 + ni * 16 + l15;
        bf[ni] = *(const half8*)&Bs[c * 72 + ks * 32 + l4 * 8];
      }
#pragma unroll
      for (int mi = 0; mi < 4; ++mi)
#pragma unroll
        for (int ni = 0; ni < 4; ++ni)
          acc[mi][ni] = __builtin_amdgcn_mfma_f32_16x16x32_f16(af[mi], bf[ni], acc[mi][ni], 0, 0, 0);
    }
    __syncthreads();
  }

#pragma unroll
  for (int ni = 0; ni < 4; ++ni) {
    const int col = col0 + wc * 64 + ni * 16 + l15;
#pragma unroll
    for (int mi = 0; mi < 4; ++mi) {
      f32x4 v = acc[mi][ni];
      const int rbase = row0 + wr * 64 + mi * 16 + l4 * 4;
#pragma unroll
      for (int r = 0; r < 4; ++r)
        Wf[(size_t)(rbase + r) * Cc + col] = (_Float16)v[r];
    }
  }
}

// ---------------------------------------------------------------------------
// fp16-in MFMA GEMM:  C[r][o] = sum_c A[r][c]*W[o][c] + bias[o]
// 128x128 tile, BK=64, 4 waves. XCD-chunked bijective swizzle.
// ---------------------------------------------------------------------------
template<int F16OUT>
__global__ __launch_bounds__(256) void gemm_h16(
    const _Float16* __restrict__ A, const _Float16* __restrict__ W,
    const float* __restrict__ bias, void* __restrict__ Cout)
{
  __shared__ __align__(16) _Float16 As[128 * 64];
  __shared__ __align__(16) _Float16 Bs[128 * 64];
  const int t = threadIdx.x;
  const int nwg = gridDim.x;
  int bid = blockIdx.x;
  bid = (bid & 7) * (nwg >> 3) + (bid >> 3);
  const int colb = bid % 6, rowb = bid / 6;
  const int row0 = rowb * 128, col0 = colb * 128;
  const int lane = t & 63, w = t >> 6;
  const int wr = w >> 1, wc = w & 1;
  const int l15 = lane & 15, l4 = lane >> 4;
  const int srow = t >> 3;
  const int sg   = t & 7;

  f32x4 acc[4][4];
#pragma unroll
  for (int i = 0; i < 4; ++i)
#pragma unroll
    for (int j = 0; j < 4; ++j) acc[i][j] = (f32x4){0.f, 0.f, 0.f, 0.f};

  for (int kt = 0; kt < 12; ++kt) {
    const int k0 = kt * 64;
#pragma unroll
    for (int it = 0; it < 4; ++it) {
      const int r = it * 32 + srow;
      half8 ha = *(const half8*)(A + (size_t)(row0 + r) * Cc + k0 + sg * 8);
      half8 hw = *(const half8*)(W + (size_t)(col0 + r) * Cc + k0 + sg * 8);
      const int dst = r * 64 + ((sg ^ (r & 7)) * 8);
      *(half8*)&As[dst] = ha;
      *(half8*)&Bs[dst] = hw;
    }
    __syncthreads();
#pragma unroll
    for (int ks = 0; ks < 2; ++ks) {
      half8 af[4], bf[4];
#pragma unroll
      for (int mi = 0; mi < 4; ++mi) {
        const int r = wr * 64 + mi * 16 + l15;
        const int g = ks * 4 + l4;
        af[mi] = *(const half8*)&As[r * 64 + ((g ^ (r & 7)) * 8)];
      }
#pragma unroll
      for (int ni = 0; ni < 4; ++ni) {
        const int r = wc * 64 + ni * 16 + l15;
        const int g = ks * 4 + l4;
        bf[ni] = *(const half8*)&Bs[r * 64 + ((g ^ (r & 7)) * 8)];
      }
#pragma unroll
      for (int mi = 0; mi < 4; ++mi)
#pragma unroll
        for (int ni = 0; ni < 4; ++ni)
          acc[mi][ni] = __builtin_amdgcn_mfma_f32_16x16x32_f16(af[mi], bf[ni], acc[mi][ni], 0, 0, 0);
    }
    __syncthreads();
  }

#pragma unroll
  for (int ni = 0; ni < 4; ++ni) {
    const int col = col0 + wc * 64 + ni * 16 + l15;
    const float bcol = bias[col];
#pragma unroll
    for (int mi = 0; mi < 4; ++mi) {
      f32x4 v = acc[mi][ni];
      const int rbase = row0 + wr * 64 + mi * 16 + l4 * 4;
#pragma unroll
      for (int r = 0; r < 4; ++r) {
        if (F16OUT) {
          ((_Float16*)Cout)[(size_t)(rbase + r) * Cc + col] = (_Float16)(v[r] + bcol);
        } else {
          ((float*)Cout)[(size_t)(rbase + r) * Cc + col] = v[r] + bcol;
        }
      }
    }
  }
}

// ---------------------------------------------------------------------------
// Dual-output K+V GEMM (stacked Wk||Wv), A staged once.
// ---------------------------------------------------------------------------
__global__ __launch_bounds__(256) void gemm_h16_kv(
    const _Float16* __restrict__ A, const _Float16* __restrict__ Wkv,
    const float* __restrict__ bk, const float* __restrict__ bv,
    _Float16* __restrict__ K16, _Float16* __restrict__ V16)
{
  __shared__ __align__(16) _Float16 As[128 * 64];
  __shared__ __align__(16) _Float16 Bs[128 * 64];
  const int t = threadIdx.x;
  const int nwg = gridDim.x;
  int bid = blockIdx.x;
  bid = (bid & 7) * (nwg >> 3) + (bid >> 3);   // nwg = 2352, %8 == 0
  const int colb = bid % 12, rowb = bid / 12;
  const int row0 = rowb * 128, col0 = colb * 128;
  const int lane = t & 63, w = t >> 6;
  const int wr = w >> 1, wc = w & 1;
  const int l15 = lane & 15, l4 = lane >> 4;
  const int srow = t >> 3;
  const int sg   = t & 7;

  _Float16* Cout = (colb < 6) ? K16 : V16;
  const float* bias = (colb < 6) ? bk : bv;
  const int cadj = (colb < 6) ? 0 : Cc;

  f32x4 acc[4][4];
#pragma unroll
  for (int i = 0; i < 4; ++i)
#pragma unroll
    for (int j = 0; j < 4; ++j) acc[i][j] = (f32x4){0.f, 0.f, 0.f, 0.f};

  for (int kt = 0; kt < 12; ++kt) {
    const int k0 = kt * 64;
#pragma unroll
    for (int it = 0; it < 4; ++it) {
      const int r = it * 32 + srow;
      half8 ha = *(const half8*)(A + (size_t)(row0 + r) * Cc + k0 + sg * 8);
      half8 hw = *(const half8*)(Wkv + (size_t)(col0 + r) * Cc + k0 + sg * 8);
      const int dst = r * 64 + ((sg ^ (r & 7)) * 8);
      *(half8*)&As[dst] = ha;
      *(half8*)&Bs[dst] = hw;
    }
    __syncthreads();
#pragma unroll
    for (int ks = 0; ks < 2; ++ks) {
      half8 af[4], bf[4];
#pragma unroll
      for (int mi = 0; mi < 4; ++mi) {
        const int r = wr * 64 + mi * 16 + l15;
        const int g = ks * 4 + l4;
        af[mi] = *(const half8*)&As[r * 64 + ((g ^ (r & 7)) * 8)];
      }
#pragma unroll
      for (int ni = 0; ni < 4; ++ni) {
        const int r = wc * 64 + ni * 16 + l15;
        const int g = ks * 4 + l4;
        bf[ni] = *(const half8*)&Bs[r * 64 + ((g ^ (r & 7)) * 8)];
      }
#pragma unroll
      for (int mi = 0; mi < 4; ++mi)
#pragma unroll
        for (int ni = 0; ni < 4; ++ni)
          acc[mi][ni] = __builtin_amdgcn_mfma_f32_16x16x32_f16(af[mi], bf[ni], acc[mi][ni], 0, 0, 0);
    }
    __syncthreads();
  }

#pragma unroll
  for (int ni = 0; ni < 4; ++ni) {
    const int col = col0 + wc * 64 + ni * 16 + l15;
    const float bcol = bias[col - cadj];
#pragma unroll
    for (int mi = 0; mi < 4; ++mi) {
      f32x4 v = acc[mi][ni];
      const int rbase = row0 + wr * 64 + mi * 16 + l4 * 4;
#pragma unroll
      for (int r = 0; r < 4; ++r)
        Cout[(size_t)(rbase + r) * Cc + (col - cadj)] = (_Float16)(v[r] + bcol);
    }
  }
}

// ---------------------------------------------------------------------------
// Offset network + bilinear sampling: one block (512 thr) per (b,g).
// ---------------------------------------------------------------------------
__global__ __launch_bounds__(512, 4) void offset_sample(
    const _Float16* __restrict__ Q16, const float* __restrict__ hidden,
    const float* __restrict__ dw_w, const float* __restrict__ dw_b,
    const float* __restrict__ ln_w, const float* __restrict__ ln_b,
    const float* __restrict__ pw_w, _Float16* __restrict__ XS)
{
  __shared__ float Qs[Nn * CgC];   // 75.3 KB
  const int tid = threadIdx.x;
  const int g = blockIdx.x;        // 0..7
  const int b = blockIdx.y;        // 0..127
  const int cl = tid & 31;
  const int grp = tid >> 5;        // 0..15

  const size_t base = (size_t)b * Nn * Cc + g * CgC;
  for (int i = tid; i < Nn * 12; i += 512) {
    const int n = i / 12, j = i - n * 12;
    half8 hv = *(const half8*)(Q16 + base + (size_t)n * Cc + j * 8);
#pragma unroll
    for (int e = 0; e < 8; ++e) Qs[n * CgC + j * 8 + e] = (float)hv[e];
  }

  float wdw[3][9], bdw[3], wln[3], bln[3], wp0[3], wp1[3];
#pragma unroll
  for (int k = 0; k < 3; ++k) {
    const int c = cl + k * 32;
#pragma unroll
    for (int t9 = 0; t9 < 9; ++t9) wdw[k][t9] = dw_w[c * 9 + t9];
    bdw[k] = dw_b[c];
    wln[k] = ln_w[c];
    bln[k] = ln_b[c];
    wp0[k] = pw_w[c];
    wp1[k] = pw_w[CgC + c];
  }
  __syncthreads();

  const float* hb0 = hidden + base;

  for (int s0 = 0; s0 < Nn; s0 += 16) {
    const int site = s0 + grp;
    if (site >= Nn) break;
    const int h = site / Ww, w = site % Ww;

    float t[3];
#pragma unroll
    for (int k = 0; k < 3; ++k) t[k] = bdw[k];
#pragma unroll
    for (int ky = 0; ky < 3; ++ky) {
      const int hp = h + ky - 1;
      if (hp < 0 || hp > Hh - 1) continue;
#pragma unroll
      for (int kx = 0; kx < 3; ++kx) {
        const int wp = w + kx - 1;
        if (wp < 0 || wp > Ww - 1) continue;
        const float* row = &Qs[(hp * Ww + wp) * CgC + cl];
#pragma unroll
        for (int k = 0; k < 3; ++k)
          t[k] = fmaf(row[k * 32], wdw[k][ky * 3 + kx], t[k]);
      }
    }

    float s = t[0] + t[1] + t[2];
#pragma unroll
    for (int off = 1; off <= 16; off <<= 1) s += __shfl_xor(s, off, 32);
    const float mu = s * (1.f / 96.f);
    float d2 = 0.f;
#pragma unroll
    for (int k = 0; k < 3; ++k) { const float d = t[k] - mu; d2 = fmaf(d, d, d2); }
#pragma unroll
    for (int off = 1; off <= 16; off <<= 1) d2 += __shfl_xor(d2, off, 32);
    const float rstd = rsqrtf(d2 * (1.f / 96.f) + 1e-5f);

    float p0 = 0.f, p1 = 0.f;
#pragma unroll
    for (int k = 0; k < 3; ++k) {
      const float tn = (t[k] - mu) * rstd * wln[k] + bln[k];
      const float a = 0.5f * tn * (1.f + erff(tn * 0.70710678118654752f));
      p0 = fmaf(a, wp0[k], p0);
      p1 = fmaf(a, wp1[k], p1);
    }
#pragma unroll
    for (int off = 1; off <= 16; off <<= 1) {
      p0 += __shfl_xor(p0, off, 32);
      p1 += __shfl_xor(p1, off, 32);
    }

    const float offy = tanhf(p0) * (1.f / 13.f);
    const float offx = tanhf(p1) * (1.f / 13.f);
    const float refy = (h + 0.5f) / 14.f * 2.f - 1.f;
    const float refx = (w + 0.5f) / 14.f * 2.f - 1.f;
    const float gx = ((offx + refx) + 1.f) * 0.5f * 13.f;
    const float gy = ((offy + refy) + 1.f) * 0.5f * 13.f;

    const float x0f = floorf(gx), y0f = floorf(gy);
    const int x0 = (int)x0f, y0 = (int)y0f;
    const float wx1 = gx - x0f, wx0 = 1.f - wx1;
    const float wy1 = gy - y0f, wy0 = 1.f - wy1;
    const bool vx0 = (x0 >= 0) & (x0 <= 13), vx1 = (x0 + 1 >= 0) & (x0 + 1 <= 13);
    const bool vy0 = (y0 >= 0) & (y0 <= 13), vy1 = (y0 + 1 >= 0) & (y0 + 1 <= 13);
    float acc[3] = {0.f, 0.f, 0.f};
#pragma unroll
    for (int k = 0; k < 3; ++k) {
      const int c = cl + k * 32;
      if (vx0 & vy0) acc[k] = fmaf(wx0 * wy0, hb0[(size_t)(y0 * Ww + x0) * Cc + c], acc[k]);
      if (vx1 & vy0) acc[k] = fmaf(wx1 * wy0, hb0[(size_t)(y0 * Ww + x0 + 1) * Cc + c], acc[k]);
      if (vx0 & vy1) acc[k] = fmaf(wx0 * wy1, hb0[(size_t)((y0 + 1) * Ww + x0) * Cc + c], acc[k]);
      if (vx1 & vy1) acc[k] = fmaf(wx1 * wy1, hb0[(size_t)((y0 + 1) * Ww + x0 + 1) * Cc + c], acc[k]);
    }
    _Float16* xp = XS + ((size_t)b * Nn + site) * Cc + g * CgC + cl;
#pragma unroll
    for (int k = 0; k < 3; ++k) xp[k * 32] = (_Float16)acc[k];
  }
}

// ---------------------------------------------------------------------------
// Fused attention: one block of 8 waves (512 thr) per (b, h), fp16 inputs.
// LDS 69.9 KB -> 2 blocks/CU, 16 waves/CU.
// ---------------------------------------------------------------------------
__global__ __launch_bounds__(512, 4) void attn_fused(
    const _Float16* __restrict__ Qm, const _Float16* __restrict__ Km,
    const _Float16* __restrict__ Vm, float* __restrict__ attn,
    _Float16* __restrict__ OUT)
{
  __shared__ __align__(16) _Float16 Kt[208 * 72];
  __shared__ __align__(16) _Float16 Vt[64 * 232];
  __shared__ __align__(16) _Float16 Ps[8][16 * 40];
  const int tid = threadIdx.x;
  const int hh = blockIdx.x, b = blockIdx.y;
  const int lane = tid & 63, wv = tid >> 6;
  const int l15 = lane & 15, l4 = lane >> 4;

  const _Float16* Qbase = Qm + (size_t)b * Nn * Cc + hh * Dh;
  const _Float16* Kbase = Km + (size_t)b * Nn * Cc + hh * Dh;
  const _Float16* Vbase = Vm + (size_t)b * Nn * Cc + hh * Dh;

  {
    const int g = tid & 7;
    for (int n = tid >> 3; n < 208; n += 64) {
      half8 hv = {};
      if (n < Nn) hv = *(const half8*)(Kbase + (size_t)n * Cc + g * 8);
      *(half8*)&Kt[n * 72 + g * 8] = hv;
    }
  }
  {
    const int d0 = (tid & 15) * 4;
    for (int n = tid >> 4; n < Nn; n += 32) {
      half4 v = *(const half4*)(Vbase + (size_t)n * Cc + d0);
      Vt[(d0 + 0) * 232 + n] = v[0];
      Vt[(d0 + 1) * 232 + n] = v[1];
      Vt[(d0 + 2) * 232 + n] = v[2];
      Vt[(d0 + 3) * 232 + n] = v[3];
    }
    for (int e = tid; e < 64 * 36; e += 512) {
      int d = e / 36, n = Nn + e % 36;
      Vt[d * 232 + n] = (_Float16)0.f;
    }
  }
  __syncthreads();

  for (int mt = wv; mt < 13; mt += 8) {
    const int qrow = mt * 16 + l15;
    const _Float16* qp = Qbase + (size_t)(qrow < Nn ? qrow : (Nn - 1)) * Cc + l4 * 8;
    half8 aq0 = *(const half8*)qp;
    half8 aq1 = *(const half8*)(qp + 32);

    f32x4 accs[13];
#pragma unroll
    for (int nt = 0; nt < 13; ++nt) accs[nt] = (f32x4){0.f, 0.f, 0.f, 0.f};
#pragma unroll
    for (int nt = 0; nt < 13; ++nt) {
      const int rb = (nt * 16 + l15) * 72;
      half8 bk0 = *(const half8*)&Kt[rb + l4 * 8];
      half8 bk1 = *(const half8*)&Kt[rb + 32 + l4 * 8];
      accs[nt] = __builtin_amdgcn_mfma_f32_16x16x32_f16(aq0, bk0, accs[nt], 0, 0, 0);
      accs[nt] = __builtin_amdgcn_mfma_f32_16x16x32_f16(aq1, bk1, accs[nt], 0, 0, 0);
    }

    float rmax[4] = {-1e30f, -1e30f, -1e30f, -1e30f};
#pragma unroll
    for (int nt = 0; nt < 13; ++nt) {
#pragma unroll
      for (int r = 0; r < 4; ++r) {
        float s = accs[nt][r] * 0.125f;
        if (nt == 12 && l15 >= 4) s = -1e30f;
        accs[nt][r] = s;
        rmax[r] = fmaxf(rmax[r], s);
      }
    }
#pragma unroll
    for (int off = 1; off <= 8; off <<= 1)
#pragma unroll
      for (int r = 0; r < 4; ++r)
        rmax[r] = fmaxf(rmax[r], __shfl_xor(rmax[r], off, 64));

    float rsum[4] = {0.f, 0.f, 0.f, 0.f};
#pragma unroll
    for (int nt = 0; nt < 13; ++nt) {
#pragma unroll
      for (int r = 0; r < 4; ++r) {
        float p = __expf(accs[nt][r] - rmax[r]);
        accs[nt][r] = p;
        rsum[r] += p;
      }
    }
#pragma unroll
    for (int off = 1; off <= 8; off <<= 1)
#pragma unroll
      for (int r = 0; r < 4; ++r)
        rsum[r] += __shfl_xor(rsum[r], off, 64);
    float rinv[4];
#pragma unroll
    for (int r = 0; r < 4; ++r) rinv[r] = 1.f / rsum[r];

    float* ab = attn + (((size_t)b * NHh + hh) * Nn) * (size_t)Nn;
#pragma unroll
    for (int nt = 0; nt < 13; ++nt) {
      const int n = nt * 16 + l15;
#pragma unroll
      for (int r = 0; r < 4; ++r) {
        float pr = accs[nt][r] * rinv[r];
        accs[nt][r] = pr;
        const int m = mt * 16 + l4 * 4 + r;
        if (m < Nn && n < Nn) ab[(size_t)m * Nn + n] = pr;
      }
    }

    f32x4 acco[4];
#pragma unroll
    for (int dt = 0; dt < 4; ++dt) acco[dt] = (f32x4){0.f, 0.f, 0.f, 0.f};
#pragma unroll
    for (int nsl = 0; nsl < 7; ++nsl) {
#pragma unroll
      for (int h2 = 0; h2 < 2; ++h2) {
        const int nt = nsl * 2 + h2;
        if (nt < 13) {
#pragma unroll
          for (int r = 0; r < 4; ++r)
            Ps[wv][(l4 * 4 + r) * 40 + h2 * 16 + l15] = (_Float16)accs[nt][r];
        } else {
#pragma unroll
          for (int r = 0; r < 4; ++r)
            Ps[wv][(l4 * 4 + r) * 40 + h2 * 16 + l15] = (_Float16)0.f;
        }
      }
      half8 ap = *(const half8*)&Ps[wv][l15 * 40 + l4 * 8];
#pragma unroll
      for (int dt = 0; dt < 4; ++dt) {
        half8 bv = *(const half8*)&Vt[(dt * 16 + l15) * 232 + nsl * 32 + l4 * 8];
        acco[dt] = __builtin_amdgcn_mfma_f32_16x16x32_f16(ap, bv, acco[dt], 0, 0, 0);
      }
    }
#pragma unroll
    for (int dt = 0; dt < 4; ++dt) {
#pragma unroll
      for (int r = 0; r < 4; ++r) {
        const int m = mt * 16 + l4 * 4 + r;
        if (m < Nn)
          OUT[((size_t)b * Nn + m) * Cc + hh * Dh + dt * 16 + l15] = (_Float16)acco[dt][r];
      }
    }
  }
}

// ---------------------------------------------------------------------------
extern "C" void kernel_launch(void* const* d_in, const int* in_sizes, int n_in,
                              void* d_out, int out_size, void* d_ws, size_t ws_size,
                              hipStream_t stream) {
  const float* hidden = (const float*)d_in[0];
  const float* Wq = (const float*)d_in[1];
  const float* bq = (const float*)d_in[2];
  const float* dw_w = (const float*)d_in[3];
  const float* dw_b = (const float*)d_in[4];
  const float* ln_w = (const float*)d_in[5];
  const float* ln_b = (const float*)d_in[6];
  const float* pw_w = (const float*)d_in[7];
  const float* Wk = (const float*)d_in[8];
  const float* bk = (const float*)d_in[9];
  const float* Wv = (const float*)d_in[10];
  const float* bv = (const float*)d_in[11];
  const float* Wp = (const float*)d_in[12];
  const float* bp = (const float*)d_in[13];
  const float* Wo = (const float*)d_in[14];
  const float* bo = (const float*)d_in[15];

  const size_t SZ = (size_t)Bsz * Nn * Cc;      // 19,267,584
  float* yout = (float*)d_out;                  // (B,N,C) fp32
  float* attn = yout + SZ;                      // (B,12,196,196) fp32 probs

  _Float16* h16   = (_Float16*)d_ws;            // fp16 workspace buffers
  _Float16* Q16   = h16   + SZ;
  _Float16* XS16  = Q16   + SZ;
  _Float16* K16   = XS16  + SZ;
  _Float16* V16   = K16   + SZ;
  _Float16* OUT16 = V16   + SZ;
  _Float16* W16   = OUT16 + SZ;                 // 5 x 768 x 768 (Wq,Wk,Wv,Wp,Wo)
  _Float16* Wf16  = W16   + 5 * (size_t)Cc * Cc;  // fused Wo@Wp
  float*    bf    = (float*)(Wf16 + (size_t)Cc * Cc);  // fused bias (768)

  const int gemm_blocks = (ROWS / 128) * (Cc / 128);  // 1176
  const int kv_blocks   = (ROWS / 128) * 12;          // 2352
  const int n8 = (int)(SZ / 8);

  // 0. one-shot conversions + fused proj*out weight
  cvt_f32_f16<<<(n8 + 255) / 256, 256, 0, stream>>>(hidden, h16, n8);
  cvt_w5<<<(5 * Cc * Cc / 8 + 255) / 256, 256, 0, stream>>>(Wq, Wk, Wv, Wp, Wo, W16);
  gemm_ww<<<36, 256, 0, stream>>>(W16 + 4 * (size_t)Cc * Cc, W16 + 3 * (size_t)Cc * Cc, Wf16);
  fuse_bias<<<(Cc + 255) / 256, 256, 0, stream>>>(Wo, bp, bo, bf);

  // 1. Q16 = hidden @ Wq^T + bq
  gemm_h16<1><<<gemm_blocks, 256, 0, stream>>>(h16, W16 + 0 * (size_t)Cc * Cc, bq, Q16);
  // 2. offset network + bilinear sampling -> XS16
  offset_sample<<<dim3(Gg, Bsz), 512, 0, stream>>>(Q16, hidden, dw_w, dw_b, ln_w, ln_b, pw_w, XS16);
  // 3. K16,V16 in one dispatch (stacked Wk||Wv, A staged once)
  gemm_h16_kv<<<kv_blocks, 256, 0, stream>>>(XS16, W16 + 1 * (size_t)Cc * Cc, bk, bv, K16, V16);
  // 4. fused scores+softmax+PV -> attn (fp32 probs) + OUT16
  attn_fused<<<dim3(NHh, Bsz), 512, 0, stream>>>(Q16, K16, V16, attn, OUT16);
  // 5. y = OUT16 @ (Wo@Wp)^T + (Wo@bp + bo) -> d_out (fp32), proj+out fused
  gemm_h16<0><<<gemm_blocks, 256, 0, stream>>>(OUT16, Wf16, bf, yout);
}

// Round 10
// 525.434 us; speedup vs baseline: 1.0435x; 1.0435x over previous
//
#include <hip/hip_runtime.h>
#include <math.h>

#define Bsz 128
#define Hh 14
#define Ww 14
#define Nn 196
#define Cc 768
#define Gg 8
#define CgC 96
#define NHh 12
#define Dh 64
#define ROWS (Bsz*Nn)   // 25088

typedef _Float16 half8 __attribute__((ext_vector_type(8)));
typedef _Float16 half4 __attribute__((ext_vector_type(4)));
typedef float f32x4 __attribute__((ext_vector_type(4)));

// ---------------------------------------------------------------------------
// weights fp32 -> fp16 (one-shot)
// ---------------------------------------------------------------------------
__global__ __launch_bounds__(256) void cvt_w5(
    const float* __restrict__ w0, const float* __restrict__ w1,
    const float* __restrict__ w2, const float* __restrict__ w3,
    const float* __restrict__ w4, _Float16* __restrict__ dst)
{
  const int i = blockIdx.x * 256 + threadIdx.x;   // per 8 elems
  const int per = Cc * Cc / 8;                    // 73728
  if (i >= 5 * per) return;
  const int m = i / per, r = i - m * per;
  const float* s = (m == 0) ? w0 : (m == 1) ? w1 : (m == 2) ? w2 : (m == 3) ? w3 : w4;
  float4 a = *(const float4*)(s + (size_t)r * 8);
  float4 b = *(const float4*)(s + (size_t)r * 8 + 4);
  half8 h;
  h[0]=(_Float16)a.x; h[1]=(_Float16)a.y; h[2]=(_Float16)a.z; h[3]=(_Float16)a.w;
  h[4]=(_Float16)b.x; h[5]=(_Float16)b.y; h[6]=(_Float16)b.z; h[7]=(_Float16)b.w;
  *(half8*)(dst + (size_t)m * Cc * Cc + (size_t)r * 8) = h;
}

// ---------------------------------------------------------------------------
// b' = Wo @ bproj + bout  -- PARALLEL: one block per output, tree reduce.
// ---------------------------------------------------------------------------
__global__ __launch_bounds__(256) void fuse_bias(
    const float* __restrict__ Wo, const float* __restrict__ bp,
    const float* __restrict__ bo, float* __restrict__ bf)
{
  __shared__ float red[256];
  const int o2 = blockIdx.x;           // 0..767
  const int tid = threadIdx.x;
  const float* wrow = Wo + (size_t)o2 * Cc;
  float s = 0.f;
  for (int o = tid; o < Cc; o += 256) s = fmaf(wrow[o], bp[o], s);
  red[tid] = s;
  __syncthreads();
  for (int st = 128; st > 0; st >>= 1) { if (tid < st) red[tid] += red[tid + st]; __syncthreads(); }
  if (tid == 0) bf[o2] = red[0] + bo[o2];
}

// ---------------------------------------------------------------------------
// W' = Wo @ Wp  (768x768, fp16 in/out, fp32 accum). 36 blocks (6x6), BK=64.
// ---------------------------------------------------------------------------
__global__ __launch_bounds__(256) void gemm_ww(
    const _Float16* __restrict__ Wo16, const _Float16* __restrict__ Wp16,
    _Float16* __restrict__ Wf)
{
  __shared__ __align__(16) _Float16 As[128 * 64];
  __shared__ __align__(16) _Float16 Bs[128 * 72];
  const int t = threadIdx.x;
  const int bid = blockIdx.x;
  const int colb = bid % 6, rowb = bid / 6;
  const int row0 = rowb * 128, col0 = colb * 128;
  const int lane = t & 63, w = t >> 6;
  const int wr = w >> 1, wc = w & 1;
  const int l15 = lane & 15, l4 = lane >> 4;
  const int srow = t >> 3;
  const int sg   = t & 7;

  f32x4 acc[4][4];
#pragma unroll
  for (int i = 0; i < 4; ++i)
#pragma unroll
    for (int j = 0; j < 4; ++j) acc[i][j] = (f32x4){0.f, 0.f, 0.f, 0.f};

  for (int kt = 0; kt < 12; ++kt) {
    const int k0 = kt * 64;
#pragma unroll
    for (int it = 0; it < 4; ++it) {
      const int r = it * 32 + srow;
      half8 ha = *(const half8*)(Wo16 + (size_t)(row0 + r) * Cc + k0 + sg * 8);
      *(half8*)&As[r * 64 + ((sg ^ (r & 7)) * 8)] = ha;
    }
    {
      const int og = t >> 4;
      const int cg = t & 15;
#pragma unroll
      for (int it = 0; it < 4; ++it) {
        const int o = it * 16 + og;
        half8 hv = *(const half8*)(Wp16 + (size_t)(k0 + o) * Cc + col0 + cg * 8);
#pragma unroll
        for (int e = 0; e < 8; ++e)
          Bs[(cg * 8 + e) * 72 + o] = hv[e];
      }
    }
    __syncthreads();
#pragma unroll
    for (int ks = 0; ks < 2; ++ks) {
      half8 af[4], bf[4];
#pragma unroll
      for (int mi = 0; mi < 4; ++mi) {
        const int r = wr * 64 + mi * 16 + l15;
        const int g = ks * 4 + l4;
        af[mi] = *(const half8*)&As[r * 64 + ((g ^ (r & 7)) * 8)];
      }
#pragma unroll
      for (int ni = 0; ni < 4; ++ni) {
        const int c = wc * 64 + ni * 16 + l15;
        bf[ni] = *(const half8*)&Bs[c * 72 + ks * 32 + l4 * 8];
      }
#pragma unroll
      for (int mi = 0; mi < 4; ++mi)
#pragma unroll
        for (int ni = 0; ni < 4; ++ni)
          acc[mi][ni] = __builtin_amdgcn_mfma_f32_16x16x32_f16(af[mi], bf[ni], acc[mi][ni], 0, 0, 0);
    }
    __syncthreads();
  }

#pragma unroll
  for (int ni = 0; ni < 4; ++ni) {
    const int col = col0 + wc * 64 + ni * 16 + l15;
#pragma unroll
    for (int mi = 0; mi < 4; ++mi) {
      f32x4 v = acc[mi][ni];
      const int rbase = row0 + wr * 64 + mi * 16 + l4 * 4;
#pragma unroll
      for (int r = 0; r < 4; ++r)
        Wf[(size_t)(rbase + r) * Cc + col] = (_Float16)v[r];
    }
  }
}

// ---------------------------------------------------------------------------
// Q GEMM with fp32 A (hidden) + fp16 W: cvt folded into staging.
// ---------------------------------------------------------------------------
__global__ __launch_bounds__(256) void gemm_f32a(
    const float* __restrict__ A, const _Float16* __restrict__ W,
    const float* __restrict__ bias, _Float16* __restrict__ Cout)
{
  __shared__ __align__(16) _Float16 As[128 * 64];
  __shared__ __align__(16) _Float16 Bs[128 * 64];
  const int t = threadIdx.x;
  const int nwg = gridDim.x;
  int bid = blockIdx.x;
  bid = (bid & 7) * (nwg >> 3) + (bid >> 3);
  const int colb = bid % 6, rowb = bid / 6;
  const int row0 = rowb * 128, col0 = colb * 128;
  const int lane = t & 63, w = t >> 6;
  const int wr = w >> 1, wc = w & 1;
  const int l15 = lane & 15, l4 = lane >> 4;
  const int srow = t >> 3;
  const int sg   = t & 7;

  f32x4 acc[4][4];
#pragma unroll
  for (int i = 0; i < 4; ++i)
#pragma unroll
    for (int j = 0; j < 4; ++j) acc[i][j] = (f32x4){0.f, 0.f, 0.f, 0.f};

  for (int kt = 0; kt < 12; ++kt) {
    const int k0 = kt * 64;
#pragma unroll
    for (int it = 0; it < 4; ++it) {
      const int r = it * 32 + srow;
      const float* ap = A + (size_t)(row0 + r) * Cc + k0 + sg * 8;
      float4 a0 = *(const float4*)ap;
      float4 a1 = *(const float4*)(ap + 4);
      half8 ha;
      ha[0]=(_Float16)a0.x; ha[1]=(_Float16)a0.y; ha[2]=(_Float16)a0.z; ha[3]=(_Float16)a0.w;
      ha[4]=(_Float16)a1.x; ha[5]=(_Float16)a1.y; ha[6]=(_Float16)a1.z; ha[7]=(_Float16)a1.w;
      half8 hw = *(const half8*)(W + (size_t)(col0 + r) * Cc + k0 + sg * 8);
      const int dst = r * 64 + ((sg ^ (r & 7)) * 8);
      *(half8*)&As[dst] = ha;
      *(half8*)&Bs[dst] = hw;
    }
    __syncthreads();
#pragma unroll
    for (int ks = 0; ks < 2; ++ks) {
      half8 af[4], bf[4];
#pragma unroll
      for (int mi = 0; mi < 4; ++mi) {
        const int r = wr * 64 + mi * 16 + l15;
        const int g = ks * 4 + l4;
        af[mi] = *(const half8*)&As[r * 64 + ((g ^ (r & 7)) * 8)];
      }
#pragma unroll
      for (int ni = 0; ni < 4; ++ni) {
        const int r = wc * 64 + ni * 16 + l15;
        const int g = ks * 4 + l4;
        bf[ni] = *(const half8*)&Bs[r * 64 + ((g ^ (r & 7)) * 8)];
      }
#pragma unroll
      for (int mi = 0; mi < 4; ++mi)
#pragma unroll
        for (int ni = 0; ni < 4; ++ni)
          acc[mi][ni] = __builtin_amdgcn_mfma_f32_16x16x32_f16(af[mi], bf[ni], acc[mi][ni], 0, 0, 0);
    }
    __syncthreads();
  }

#pragma unroll
  for (int ni = 0; ni < 4; ++ni) {
    const int col = col0 + wc * 64 + ni * 16 + l15;
    const float bcol = bias[col];
#pragma unroll
    for (int mi = 0; mi < 4; ++mi) {
      f32x4 v = acc[mi][ni];
      const int rbase = row0 + wr * 64 + mi * 16 + l4 * 4;
#pragma unroll
      for (int r = 0; r < 4; ++r)
        Cout[(size_t)(rbase + r) * Cc + col] = (_Float16)(v[r] + bcol);
    }
  }
}

// ---------------------------------------------------------------------------
// fp16-in MFMA GEMM (final, fp32 out).
// ---------------------------------------------------------------------------
template<int F16OUT>
__global__ __launch_bounds__(256) void gemm_h16(
    const _Float16* __restrict__ A, const _Float16* __restrict__ W,
    const float* __restrict__ bias, void* __restrict__ Cout)
{
  __shared__ __align__(16) _Float16 As[128 * 64];
  __shared__ __align__(16) _Float16 Bs[128 * 64];
  const int t = threadIdx.x;
  const int nwg = gridDim.x;
  int bid = blockIdx.x;
  bid = (bid & 7) * (nwg >> 3) + (bid >> 3);
  const int colb = bid % 6, rowb = bid / 6;
  const int row0 = rowb * 128, col0 = colb * 128;
  const int lane = t & 63, w = t >> 6;
  const int wr = w >> 1, wc = w & 1;
  const int l15 = lane & 15, l4 = lane >> 4;
  const int srow = t >> 3;
  const int sg   = t & 7;

  f32x4 acc[4][4];
#pragma unroll
  for (int i = 0; i < 4; ++i)
#pragma unroll
    for (int j = 0; j < 4; ++j) acc[i][j] = (f32x4){0.f, 0.f, 0.f, 0.f};

  for (int kt = 0; kt < 12; ++kt) {
    const int k0 = kt * 64;
#pragma unroll
    for (int it = 0; it < 4; ++it) {
      const int r = it * 32 + srow;
      half8 ha = *(const half8*)(A + (size_t)(row0 + r) * Cc + k0 + sg * 8);
      half8 hw = *(const half8*)(W + (size_t)(col0 + r) * Cc + k0 + sg * 8);
      const int dst = r * 64 + ((sg ^ (r & 7)) * 8);
      *(half8*)&As[dst] = ha;
      *(half8*)&Bs[dst] = hw;
    }
    __syncthreads();
#pragma unroll
    for (int ks = 0; ks < 2; ++ks) {
      half8 af[4], bf[4];
#pragma unroll
      for (int mi = 0; mi < 4; ++mi) {
        const int r = wr * 64 + mi * 16 + l15;
        const int g = ks * 4 + l4;
        af[mi] = *(const half8*)&As[r * 64 + ((g ^ (r & 7)) * 8)];
      }
#pragma unroll
      for (int ni = 0; ni < 4; ++ni) {
        const int r = wc * 64 + ni * 16 + l15;
        const int g = ks * 4 + l4;
        bf[ni] = *(const half8*)&Bs[r * 64 + ((g ^ (r & 7)) * 8)];
      }
#pragma unroll
      for (int mi = 0; mi < 4; ++mi)
#pragma unroll
        for (int ni = 0; ni < 4; ++ni)
          acc[mi][ni] = __builtin_amdgcn_mfma_f32_16x16x32_f16(af[mi], bf[ni], acc[mi][ni], 0, 0, 0);
    }
    __syncthreads();
  }

#pragma unroll
  for (int ni = 0; ni < 4; ++ni) {
    const int col = col0 + wc * 64 + ni * 16 + l15;
    const float bcol = bias[col];
#pragma unroll
    for (int mi = 0; mi < 4; ++mi) {
      f32x4 v = acc[mi][ni];
      const int rbase = row0 + wr * 64 + mi * 16 + l4 * 4;
#pragma unroll
      for (int r = 0; r < 4; ++r) {
        if (F16OUT) {
          ((_Float16*)Cout)[(size_t)(rbase + r) * Cc + col] = (_Float16)(v[r] + bcol);
        } else {
          ((float*)Cout)[(size_t)(rbase + r) * Cc + col] = v[r] + bcol;
        }
      }
    }
  }
}

// ---------------------------------------------------------------------------
// Dual-output K+V GEMM (stacked Wk||Wv), A staged once.
// ---------------------------------------------------------------------------
__global__ __launch_bounds__(256) void gemm_h16_kv(
    const _Float16* __restrict__ A, const _Float16* __restrict__ Wkv,
    const float* __restrict__ bk, const float* __restrict__ bv,
    _Float16* __restrict__ K16, _Float16* __restrict__ V16)
{
  __shared__ __align__(16) _Float16 As[128 * 64];
  __shared__ __align__(16) _Float16 Bs[128 * 64];
  const int t = threadIdx.x;
  const int nwg = gridDim.x;
  int bid = blockIdx.x;
  bid = (bid & 7) * (nwg >> 3) + (bid >> 3);   // nwg = 2352, %8 == 0
  const int colb = bid % 12, rowb = bid / 12;
  const int row0 = rowb * 128, col0 = colb * 128;
  const int lane = t & 63, w = t >> 6;
  const int wr = w >> 1, wc = w & 1;
  const int l15 = lane & 15, l4 = lane >> 4;
  const int srow = t >> 3;
  const int sg   = t & 7;

  _Float16* Cout = (colb < 6) ? K16 : V16;
  const float* bias = (colb < 6) ? bk : bv;
  const int cadj = (colb < 6) ? 0 : Cc;

  f32x4 acc[4][4];
#pragma unroll
  for (int i = 0; i < 4; ++i)
#pragma unroll
    for (int j = 0; j < 4; ++j) acc[i][j] = (f32x4){0.f, 0.f, 0.f, 0.f};

  for (int kt = 0; kt < 12; ++kt) {
    const int k0 = kt * 64;
#pragma unroll
    for (int it = 0; it < 4; ++it) {
      const int r = it * 32 + srow;
      half8 ha = *(const half8*)(A + (size_t)(row0 + r) * Cc + k0 + sg * 8);
      half8 hw = *(const half8*)(Wkv + (size_t)(col0 + r) * Cc + k0 + sg * 8);
      const int dst = r * 64 + ((sg ^ (r & 7)) * 8);
      *(half8*)&As[dst] = ha;
      *(half8*)&Bs[dst] = hw;
    }
    __syncthreads();
#pragma unroll
    for (int ks = 0; ks < 2; ++ks) {
      half8 af[4], bf[4];
#pragma unroll
      for (int mi = 0; mi < 4; ++mi) {
        const int r = wr * 64 + mi * 16 + l15;
        const int g = ks * 4 + l4;
        af[mi] = *(const half8*)&As[r * 64 + ((g ^ (r & 7)) * 8)];
      }
#pragma unroll
      for (int ni = 0; ni < 4; ++ni) {
        const int r = wc * 64 + ni * 16 + l15;
        const int g = ks * 4 + l4;
        bf[ni] = *(const half8*)&Bs[r * 64 + ((g ^ (r & 7)) * 8)];
      }
#pragma unroll
      for (int mi = 0; mi < 4; ++mi)
#pragma unroll
        for (int ni = 0; ni < 4; ++ni)
          acc[mi][ni] = __builtin_amdgcn_mfma_f32_16x16x32_f16(af[mi], bf[ni], acc[mi][ni], 0, 0, 0);
    }
    __syncthreads();
  }

#pragma unroll
  for (int ni = 0; ni < 4; ++ni) {
    const int col = col0 + wc * 64 + ni * 16 + l15;
    const float bcol = bias[col - cadj];
#pragma unroll
    for (int mi = 0; mi < 4; ++mi) {
      f32x4 v = acc[mi][ni];
      const int rbase = row0 + wr * 64 + mi * 16 + l4 * 4;
#pragma unroll
      for (int r = 0; r < 4; ++r)
        Cout[(size_t)(rbase + r) * Cc + (col - cadj)] = (_Float16)(v[r] + bcol);
    }
  }
}

// ---------------------------------------------------------------------------
// Offset network + bilinear sampling: one block (512 thr) per (b,g).
// ---------------------------------------------------------------------------
__global__ __launch_bounds__(512, 4) void offset_sample(
    const _Float16* __restrict__ Q16, const float* __restrict__ hidden,
    const float* __restrict__ dw_w, const float* __restrict__ dw_b,
    const float* __restrict__ ln_w, const float* __restrict__ ln_b,
    const float* __restrict__ pw_w, _Float16* __restrict__ XS)
{
  __shared__ float Qs[Nn * CgC];   // 75.3 KB
  const int tid = threadIdx.x;
  const int g = blockIdx.x;
  const int b = blockIdx.y;
  const int cl = tid & 31;
  const int grp = tid >> 5;        // 0..15

  const size_t base = (size_t)b * Nn * Cc + g * CgC;
  for (int i = tid; i < Nn * 12; i += 512) {
    const int n = i / 12, j = i - n * 12;
    half8 hv = *(const half8*)(Q16 + base + (size_t)n * Cc + j * 8);
#pragma unroll
    for (int e = 0; e < 8; ++e) Qs[n * CgC + j * 8 + e] = (float)hv[e];
  }

  float wdw[3][9], bdw[3], wln[3], bln[3], wp0[3], wp1[3];
#pragma unroll
  for (int k = 0; k < 3; ++k) {
    const int c = cl + k * 32;
#pragma unroll
    for (int t9 = 0; t9 < 9; ++t9) wdw[k][t9] = dw_w[c * 9 + t9];
    bdw[k] = dw_b[c];
    wln[k] = ln_w[c];
    bln[k] = ln_b[c];
    wp0[k] = pw_w[c];
    wp1[k] = pw_w[CgC + c];
  }
  __syncthreads();

  const float* hb0 = hidden + base;

  for (int s0 = 0; s0 < Nn; s0 += 16) {
    const int site = s0 + grp;
    if (site >= Nn) break;
    const int h = site / Ww, w = site % Ww;

    float t[3];
#pragma unroll
    for (int k = 0; k < 3; ++k) t[k] = bdw[k];
#pragma unroll
    for (int ky = 0; ky < 3; ++ky) {
      const int hp = h + ky - 1;
      if (hp < 0 || hp > Hh - 1) continue;
#pragma unroll
      for (int kx = 0; kx < 3; ++kx) {
        const int wp = w + kx - 1;
        if (wp < 0 || wp > Ww - 1) continue;
        const float* row = &Qs[(hp * Ww + wp) * CgC + cl];
#pragma unroll
        for (int k = 0; k < 3; ++k)
          t[k] = fmaf(row[k * 32], wdw[k][ky * 3 + kx], t[k]);
      }
    }

    float s = t[0] + t[1] + t[2];
#pragma unroll
    for (int off = 1; off <= 16; off <<= 1) s += __shfl_xor(s, off, 32);
    const float mu = s * (1.f / 96.f);
    float d2 = 0.f;
#pragma unroll
    for (int k = 0; k < 3; ++k) { const float d = t[k] - mu; d2 = fmaf(d, d, d2); }
#pragma unroll
    for (int off = 1; off <= 16; off <<= 1) d2 += __shfl_xor(d2, off, 32);
    const float rstd = rsqrtf(d2 * (1.f / 96.f) + 1e-5f);

    float p0 = 0.f, p1 = 0.f;
#pragma unroll
    for (int k = 0; k < 3; ++k) {
      const float tn = (t[k] - mu) * rstd * wln[k] + bln[k];
      const float a = 0.5f * tn * (1.f + erff(tn * 0.70710678118654752f));
      p0 = fmaf(a, wp0[k], p0);
      p1 = fmaf(a, wp1[k], p1);
    }
#pragma unroll
    for (int off = 1; off <= 16; off <<= 1) {
      p0 += __shfl_xor(p0, off, 32);
      p1 += __shfl_xor(p1, off, 32);
    }

    const float offy = tanhf(p0) * (1.f / 13.f);
    const float offx = tanhf(p1) * (1.f / 13.f);
    const float refy = (h + 0.5f) / 14.f * 2.f - 1.f;
    const float refx = (w + 0.5f) / 14.f * 2.f - 1.f;
    const float gx = ((offx + refx) + 1.f) * 0.5f * 13.f;
    const float gy = ((offy + refy) + 1.f) * 0.5f * 13.f;

    const float x0f = floorf(gx), y0f = floorf(gy);
    const int x0 = (int)x0f, y0 = (int)y0f;
    const float wx1 = gx - x0f, wx0 = 1.f - wx1;
    const float wy1 = gy - y0f, wy0 = 1.f - wy1;
    const bool vx0 = (x0 >= 0) & (x0 <= 13), vx1 = (x0 + 1 >= 0) & (x0 + 1 <= 13);
    const bool vy0 = (y0 >= 0) & (y0 <= 13), vy1 = (y0 + 1 >= 0) & (y0 + 1 <= 13);
    float acc[3] = {0.f, 0.f, 0.f};
#pragma unroll
    for (int k = 0; k < 3; ++k) {
      const int c = cl + k * 32;
      if (vx0 & vy0) acc[k] = fmaf(wx0 * wy0, hb0[(size_t)(y0 * Ww + x0) * Cc + c], acc[k]);
      if (vx1 & vy0) acc[k] = fmaf(wx1 * wy0, hb0[(size_t)(y0 * Ww + x0 + 1) * Cc + c], acc[k]);
      if (vx0 & vy1) acc[k] = fmaf(wx0 * wy1, hb0[(size_t)((y0 + 1) * Ww + x0) * Cc + c], acc[k]);
      if (vx1 & vy1) acc[k] = fmaf(wx1 * wy1, hb0[(size_t)((y0 + 1) * Ww + x0 + 1) * Cc + c], acc[k]);
    }
    _Float16* xp = XS + ((size_t)b * Nn + site) * Cc + g * CgC + cl;
#pragma unroll
    for (int k = 0; k < 3; ++k) xp[k * 32] = (_Float16)acc[k];
  }
}

// ---------------------------------------------------------------------------
// Fused attention: one block of 8 waves (512 thr) per (b, h), fp16 inputs.
// LDS 69.9 KB -> 2 blocks/CU, 16 waves/CU.
// ---------------------------------------------------------------------------
__global__ __launch_bounds__(512, 4) void attn_fused(
    const _Float16* __restrict__ Qm, const _Float16* __restrict__ Km,
    const _Float16* __restrict__ Vm, float* __restrict__ attn,
    _Float16* __restrict__ OUT)
{
  __shared__ __align__(16) _Float16 Kt[208 * 72];
  __shared__ __align__(16) _Float16 Vt[64 * 232];
  __shared__ __align__(16) _Float16 Ps[8][16 * 40];
  const int tid = threadIdx.x;
  const int hh = blockIdx.x, b = blockIdx.y;
  const int lane = tid & 63, wv = tid >> 6;
  const int l15 = lane & 15, l4 = lane >> 4;

  const _Float16* Qbase = Qm + (size_t)b * Nn * Cc + hh * Dh;
  const _Float16* Kbase = Km + (size_t)b * Nn * Cc + hh * Dh;
  const _Float16* Vbase = Vm + (size_t)b * Nn * Cc + hh * Dh;

  {
    const int g = tid & 7;
    for (int n = tid >> 3; n < 208; n += 64) {
      half8 hv = {};
      if (n < Nn) hv = *(const half8*)(Kbase + (size_t)n * Cc + g * 8);
      *(half8*)&Kt[n * 72 + g * 8] = hv;
    }
  }
  {
    const int d0 = (tid & 15) * 4;
    for (int n = tid >> 4; n < Nn; n += 32) {
      half4 v = *(const half4*)(Vbase + (size_t)n * Cc + d0);
      Vt[(d0 + 0) * 232 + n] = v[0];
      Vt[(d0 + 1) * 232 + n] = v[1];
      Vt[(d0 + 2) * 232 + n] = v[2];
      Vt[(d0 + 3) * 232 + n] = v[3];
    }
    for (int e = tid; e < 64 * 36; e += 512) {
      int d = e / 36, n = Nn + e % 36;
      Vt[d * 232 + n] = (_Float16)0.f;
    }
  }
  __syncthreads();

  for (int mt = wv; mt < 13; mt += 8) {
    const int qrow = mt * 16 + l15;
    const _Float16* qp = Qbase + (size_t)(qrow < Nn ? qrow : (Nn - 1)) * Cc + l4 * 8;
    half8 aq0 = *(const half8*)qp;
    half8 aq1 = *(const half8*)(qp + 32);

    f32x4 accs[13];
#pragma unroll
    for (int nt = 0; nt < 13; ++nt) accs[nt] = (f32x4){0.f, 0.f, 0.f, 0.f};
#pragma unroll
    for (int nt = 0; nt < 13; ++nt) {
      const int rb = (nt * 16 + l15) * 72;
      half8 bk0 = *(const half8*)&Kt[rb + l4 * 8];
      half8 bk1 = *(const half8*)&Kt[rb + 32 + l4 * 8];
      accs[nt] = __builtin_amdgcn_mfma_f32_16x16x32_f16(aq0, bk0, accs[nt], 0, 0, 0);
      accs[nt] = __builtin_amdgcn_mfma_f32_16x16x32_f16(aq1, bk1, accs[nt], 0, 0, 0);
    }

    float rmax[4] = {-1e30f, -1e30f, -1e30f, -1e30f};
#pragma unroll
    for (int nt = 0; nt < 13; ++nt) {
#pragma unroll
      for (int r = 0; r < 4; ++r) {
        float s = accs[nt][r] * 0.125f;
        if (nt == 12 && l15 >= 4) s = -1e30f;
        accs[nt][r] = s;
        rmax[r] = fmaxf(rmax[r], s);
      }
    }
#pragma unroll
    for (int off = 1; off <= 8; off <<= 1)
#pragma unroll
      for (int r = 0; r < 4; ++r)
        rmax[r] = fmaxf(rmax[r], __shfl_xor(rmax[r], off, 64));

    float rsum[4] = {0.f, 0.f, 0.f, 0.f};
#pragma unroll
    for (int nt = 0; nt < 13; ++nt) {
#pragma unroll
      for (int r = 0; r < 4; ++r) {
        float p = __expf(accs[nt][r] - rmax[r]);
        accs[nt][r] = p;
        rsum[r] += p;
      }
    }
#pragma unroll
    for (int off = 1; off <= 8; off <<= 1)
#pragma unroll
      for (int r = 0; r < 4; ++r)
        rsum[r] += __shfl_xor(rsum[r], off, 64);
    float rinv[4];
#pragma unroll
    for (int r = 0; r < 4; ++r) rinv[r] = 1.f / rsum[r];

    float* ab = attn + (((size_t)b * NHh + hh) * Nn) * (size_t)Nn;
#pragma unroll
    for (int nt = 0; nt < 13; ++nt) {
      const int n = nt * 16 + l15;
#pragma unroll
      for (int r = 0; r < 4; ++r) {
        float pr = accs[nt][r] * rinv[r];
        accs[nt][r] = pr;
        const int m = mt * 16 + l4 * 4 + r;
        if (m < Nn && n < Nn) ab[(size_t)m * Nn + n] = pr;
      }
    }

    f32x4 acco[4];
#pragma unroll
    for (int dt = 0; dt < 4; ++dt) acco[dt] = (f32x4){0.f, 0.f, 0.f, 0.f};
#pragma unroll
    for (int nsl = 0; nsl < 7; ++nsl) {
#pragma unroll
      for (int h2 = 0; h2 < 2; ++h2) {
        const int nt = nsl * 2 + h2;
        if (nt < 13) {
#pragma unroll
          for (int r = 0; r < 4; ++r)
            Ps[wv][(l4 * 4 + r) * 40 + h2 * 16 + l15] = (_Float16)accs[nt][r];
        } else {
#pragma unroll
          for (int r = 0; r < 4; ++r)
            Ps[wv][(l4 * 4 + r) * 40 + h2 * 16 + l15] = (_Float16)0.f;
        }
      }
      half8 ap = *(const half8*)&Ps[wv][l15 * 40 + l4 * 8];
#pragma unroll
      for (int dt = 0; dt < 4; ++dt) {
        half8 bv = *(const half8*)&Vt[(dt * 16 + l15) * 232 + nsl * 32 + l4 * 8];
        acco[dt] = __builtin_amdgcn_mfma_f32_16x16x32_f16(ap, bv, acco[dt], 0, 0, 0);
      }
    }
#pragma unroll
    for (int dt = 0; dt < 4; ++dt) {
#pragma unroll
      for (int r = 0; r < 4; ++r) {
        const int m = mt * 16 + l4 * 4 + r;
        if (m < Nn)
          OUT[((size_t)b * Nn + m) * Cc + hh * Dh + dt * 16 + l15] = (_Float16)acco[dt][r];
      }
    }
  }
}

// ---------------------------------------------------------------------------
extern "C" void kernel_launch(void* const* d_in, const int* in_sizes, int n_in,
                              void* d_out, int out_size, void* d_ws, size_t ws_size,
                              hipStream_t stream) {
  const float* hidden = (const float*)d_in[0];
  const float* Wq = (const float*)d_in[1];
  const float* bq = (const float*)d_in[2];
  const float* dw_w = (const float*)d_in[3];
  const float* dw_b = (const float*)d_in[4];
  const float* ln_w = (const float*)d_in[5];
  const float* ln_b = (const float*)d_in[6];
  const float* pw_w = (const float*)d_in[7];
  const float* Wk = (const float*)d_in[8];
  const float* bk = (const float*)d_in[9];
  const float* Wv = (const float*)d_in[10];
  const float* bv = (const float*)d_in[11];
  const float* Wp = (const float*)d_in[12];
  const float* bp = (const float*)d_in[13];
  const float* Wo = (const float*)d_in[14];
  const float* bo = (const float*)d_in[15];

  const size_t SZ = (size_t)Bsz * Nn * Cc;      // 19,267,584
  float* yout = (float*)d_out;                  // (B,N,C) fp32
  float* attn = yout + SZ;                      // (B,12,196,196) fp32 probs

  _Float16* Q16   = (_Float16*)d_ws;            // fp16 workspace buffers
  _Float16* XS16  = Q16   + SZ;
  _Float16* K16   = XS16  + SZ;
  _Float16* V16   = K16   + SZ;
  _Float16* OUT16 = V16   + SZ;
  _Float16* W16   = OUT16 + SZ;                 // 5 x 768 x 768 (Wq,Wk,Wv,Wp,Wo)
  _Float16* Wf16  = W16   + 5 * (size_t)Cc * Cc;       // fused Wo@Wp
  float*    bf    = (float*)(Wf16 + (size_t)Cc * Cc);  // fused bias (768)

  const int gemm_blocks = (ROWS / 128) * (Cc / 128);  // 1176
  const int kv_blocks   = (ROWS / 128) * 12;          // 2352

  // 0. one-shot conversions + fused proj*out weight/bias
  cvt_w5<<<(5 * Cc * Cc / 8 + 255) / 256, 256, 0, stream>>>(Wq, Wk, Wv, Wp, Wo, W16);
  gemm_ww<<<36, 256, 0, stream>>>(W16 + 4 * (size_t)Cc * Cc, W16 + 3 * (size_t)Cc * Cc, Wf16);
  fuse_bias<<<Cc, 256, 0, stream>>>(Wo, bp, bo, bf);

  // 1. Q16 = hidden @ Wq^T + bq  (fp32 A, cvt folded into staging)
  gemm_f32a<<<gemm_blocks, 256, 0, stream>>>(hidden, W16 + 0 * (size_t)Cc * Cc, bq, Q16);
  // 2. offset network + bilinear sampling -> XS16
  offset_sample<<<dim3(Gg, Bsz), 512, 0, stream>>>(Q16, hidden, dw_w, dw_b, ln_w, ln_b, pw_w, XS16);
  // 3. K16,V16 in one dispatch (stacked Wk||Wv, A staged once)
  gemm_h16_kv<<<kv_blocks, 256, 0, stream>>>(XS16, W16 + 1 * (size_t)Cc * Cc, bk, bv, K16, V16);
  // 4. fused scores+softmax+PV -> attn (fp32 probs) + OUT16
  attn_fused<<<dim3(NHh, Bsz), 512, 0, stream>>>(Q16, K16, V16, attn, OUT16);
  // 5. y = OUT16 @ (Wo@Wp)^T + (Wo@bp + bo) -> d_out (fp32)
  gemm_h16<0><<<gemm_blocks, 256, 0, stream>>>(OUT16, Wf16, bf, yout);
}

// Round 11
// 492.796 us; speedup vs baseline: 1.1126x; 1.0662x over previous
//
#include <hip/hip_runtime.h>
#include <math.h>

#define Bsz 128
#define Hh 14
#define Ww 14
#define Nn 196
#define Cc 768
#define Gg 8
#define CgC 96
#define NHh 12
#define Dh 64
#define ROWS (Bsz*Nn)   // 25088

typedef _Float16 half8 __attribute__((ext_vector_type(8)));
typedef _Float16 half4 __attribute__((ext_vector_type(4)));
typedef float f32x4 __attribute__((ext_vector_type(4)));

typedef __attribute__((address_space(3))) void LDSv;
typedef __attribute__((address_space(1))) void GLBv;

// ---------------------------------------------------------------------------
// weights fp32 -> fp16 (one-shot)
// ---------------------------------------------------------------------------
__global__ __launch_bounds__(256) void cvt_w5(
    const float* __restrict__ w0, const float* __restrict__ w1,
    const float* __restrict__ w2, const float* __restrict__ w3,
    const float* __restrict__ w4, _Float16* __restrict__ dst)
{
  const int i = blockIdx.x * 256 + threadIdx.x;   // per 8 elems
  const int per = Cc * Cc / 8;                    // 73728
  if (i >= 5 * per) return;
  const int m = i / per, r = i - m * per;
  const float* s = (m == 0) ? w0 : (m == 1) ? w1 : (m == 2) ? w2 : (m == 3) ? w3 : w4;
  float4 a = *(const float4*)(s + (size_t)r * 8);
  float4 b = *(const float4*)(s + (size_t)r * 8 + 4);
  half8 h;
  h[0]=(_Float16)a.x; h[1]=(_Float16)a.y; h[2]=(_Float16)a.z; h[3]=(_Float16)a.w;
  h[4]=(_Float16)b.x; h[5]=(_Float16)b.y; h[6]=(_Float16)b.z; h[7]=(_Float16)b.w;
  *(half8*)(dst + (size_t)m * Cc * Cc + (size_t)r * 8) = h;
}

// ---------------------------------------------------------------------------
// b' = Wo @ bproj + bout  -- parallel tree reduce, one block per output.
// ---------------------------------------------------------------------------
__global__ __launch_bounds__(256) void fuse_bias(
    const float* __restrict__ Wo, const float* __restrict__ bp,
    const float* __restrict__ bo, float* __restrict__ bf)
{
  __shared__ float red[256];
  const int o2 = blockIdx.x;
  const int tid = threadIdx.x;
  const float* wrow = Wo + (size_t)o2 * Cc;
  float s = 0.f;
  for (int o = tid; o < Cc; o += 256) s = fmaf(wrow[o], bp[o], s);
  red[tid] = s;
  __syncthreads();
  for (int st = 128; st > 0; st >>= 1) { if (tid < st) red[tid] += red[tid + st]; __syncthreads(); }
  if (tid == 0) bf[o2] = red[0] + bo[o2];
}

// ---------------------------------------------------------------------------
// W' = Wo @ Wp  (768x768, fp16 in/out). 36 blocks, one-shot (unchanged).
// ---------------------------------------------------------------------------
__global__ __launch_bounds__(256) void gemm_ww(
    const _Float16* __restrict__ Wo16, const _Float16* __restrict__ Wp16,
    _Float16* __restrict__ Wf)
{
  __shared__ __align__(16) _Float16 As[128 * 64];
  __shared__ __align__(16) _Float16 Bs[128 * 72];
  const int t = threadIdx.x;
  const int bid = blockIdx.x;
  const int colb = bid % 6, rowb = bid / 6;
  const int row0 = rowb * 128, col0 = colb * 128;
  const int lane = t & 63, w = t >> 6;
  const int wr = w >> 1, wc = w & 1;
  const int l15 = lane & 15, l4 = lane >> 4;
  const int srow = t >> 3;
  const int sg   = t & 7;

  f32x4 acc[4][4];
#pragma unroll
  for (int i = 0; i < 4; ++i)
#pragma unroll
    for (int j = 0; j < 4; ++j) acc[i][j] = (f32x4){0.f, 0.f, 0.f, 0.f};

  for (int kt = 0; kt < 12; ++kt) {
    const int k0 = kt * 64;
#pragma unroll
    for (int it = 0; it < 4; ++it) {
      const int r = it * 32 + srow;
      half8 ha = *(const half8*)(Wo16 + (size_t)(row0 + r) * Cc + k0 + sg * 8);
      *(half8*)&As[r * 64 + ((sg ^ (r & 7)) * 8)] = ha;
    }
    {
      const int og = t >> 4;
      const int cg = t & 15;
#pragma unroll
      for (int it = 0; it < 4; ++it) {
        const int o = it * 16 + og;
        half8 hv = *(const half8*)(Wp16 + (size_t)(k0 + o) * Cc + col0 + cg * 8);
#pragma unroll
        for (int e = 0; e < 8; ++e)
          Bs[(cg * 8 + e) * 72 + o] = hv[e];
      }
    }
    __syncthreads();
#pragma unroll
    for (int ks = 0; ks < 2; ++ks) {
      half8 af[4], bf[4];
#pragma unroll
      for (int mi = 0; mi < 4; ++mi) {
        const int r = wr * 64 + mi * 16 + l15;
        const int g = ks * 4 + l4;
        af[mi] = *(const half8*)&As[r * 64 + ((g ^ (r & 7)) * 8)];
      }
#pragma unroll
      for (int ni = 0; ni < 4; ++ni) {
        const int c = wc * 64 + ni * 16 + l15;
        bf[ni] = *(const half8*)&Bs[c * 72 + ks * 32 + l4 * 8];
      }
#pragma unroll
      for (int mi = 0; mi < 4; ++mi)
#pragma unroll
        for (int ni = 0; ni < 4; ++ni)
          acc[mi][ni] = __builtin_amdgcn_mfma_f32_16x16x32_f16(af[mi], bf[ni], acc[mi][ni], 0, 0, 0);
    }
    __syncthreads();
  }

#pragma unroll
  for (int ni = 0; ni < 4; ++ni) {
    const int col = col0 + wc * 64 + ni * 16 + l15;
#pragma unroll
    for (int mi = 0; mi < 4; ++mi) {
      f32x4 v = acc[mi][ni];
      const int rbase = row0 + wr * 64 + mi * 16 + l4 * 4;
#pragma unroll
      for (int r = 0; r < 4; ++r)
        Wf[(size_t)(rbase + r) * Cc + col] = (_Float16)v[r];
    }
  }
}

// ---------------------------------------------------------------------------
// Q GEMM: fp32 A (cvt in staging, ds_write path) + fp16 W via global_load_lds.
// LDS dest linear; swizzle folded into per-lane GLOBAL source addr (rule #21).
// ---------------------------------------------------------------------------
__global__ __launch_bounds__(256) void gemm_f32a(
    const float* __restrict__ A, const _Float16* __restrict__ W,
    const float* __restrict__ bias, _Float16* __restrict__ Cout)
{
  __shared__ __align__(16) _Float16 As[128 * 64];
  __shared__ __align__(16) _Float16 Bs[128 * 64];
  const int t = threadIdx.x;
  const int nwg = gridDim.x;
  int bid = blockIdx.x;
  bid = (bid & 7) * (nwg >> 3) + (bid >> 3);
  const int colb = bid % 6, rowb = bid / 6;
  const int row0 = rowb * 128, col0 = colb * 128;
  const int lane = t & 63, w = t >> 6;
  const int wr = w >> 1, wc = w & 1;
  const int l15 = lane & 15, l4 = lane >> 4;
  const int srow = t >> 3;
  const int sg   = t & 7;
  const int rl = lane >> 3;       // 0..7 (gload row within wave chunk)
  const int sl = lane & 7;        // lds slot

  f32x4 acc[4][4];
#pragma unroll
  for (int i = 0; i < 4; ++i)
#pragma unroll
    for (int j = 0; j < 4; ++j) acc[i][j] = (f32x4){0.f, 0.f, 0.f, 0.f};

  for (int kt = 0; kt < 12; ++kt) {
    const int k0 = kt * 64;
#pragma unroll
    for (int it = 0; it < 4; ++it) {
      // W tile: direct global->LDS, linear dest, pre-swizzled source
      const int rbase = it * 32 + w * 8;
      const int rw = rbase + rl;
      const int sa = sl ^ (rw & 7);
      __builtin_amdgcn_global_load_lds(
          (GLBv*)(W + (size_t)(col0 + rw) * Cc + k0 + sa * 8),
          (LDSv*)&Bs[rbase * 64], 16, 0, 0);
      // A tile: fp32 load + cvt + swizzled ds_write
      const int r = it * 32 + srow;
      const float* ap = A + (size_t)(row0 + r) * Cc + k0 + sg * 8;
      float4 a0 = *(const float4*)ap;
      float4 a1 = *(const float4*)(ap + 4);
      half8 ha;
      ha[0]=(_Float16)a0.x; ha[1]=(_Float16)a0.y; ha[2]=(_Float16)a0.z; ha[3]=(_Float16)a0.w;
      ha[4]=(_Float16)a1.x; ha[5]=(_Float16)a1.y; ha[6]=(_Float16)a1.z; ha[7]=(_Float16)a1.w;
      *(half8*)&As[r * 64 + ((sg ^ (r & 7)) * 8)] = ha;
    }
    __syncthreads();
#pragma unroll
    for (int ks = 0; ks < 2; ++ks) {
      half8 af[4], bf[4];
#pragma unroll
      for (int mi = 0; mi < 4; ++mi) {
        const int r = wr * 64 + mi * 16 + l15;
        const int g = ks * 4 + l4;
        af[mi] = *(const half8*)&As[r * 64 + ((g ^ (r & 7)) * 8)];
      }
#pragma unroll
      for (int ni = 0; ni < 4; ++ni) {
        const int r = wc * 64 + ni * 16 + l15;
        const int g = ks * 4 + l4;
        bf[ni] = *(const half8*)&Bs[r * 64 + ((g ^ (r & 7)) * 8)];
      }
#pragma unroll
      for (int mi = 0; mi < 4; ++mi)
#pragma unroll
        for (int ni = 0; ni < 4; ++ni)
          acc[mi][ni] = __builtin_amdgcn_mfma_f32_16x16x32_f16(af[mi], bf[ni], acc[mi][ni], 0, 0, 0);
    }
    __syncthreads();
  }

#pragma unroll
  for (int ni = 0; ni < 4; ++ni) {
    const int col = col0 + wc * 64 + ni * 16 + l15;
    const float bcol = bias[col];
#pragma unroll
    for (int mi = 0; mi < 4; ++mi) {
      f32x4 v = acc[mi][ni];
      const int rbase = row0 + wr * 64 + mi * 16 + l4 * 4;
#pragma unroll
      for (int r = 0; r < 4; ++r)
        Cout[(size_t)(rbase + r) * Cc + col] = (_Float16)(v[r] + bcol);
    }
  }
}

// ---------------------------------------------------------------------------
// fp16-in MFMA GEMM (final, fp32 out) — staging via global_load_lds x2.
// ---------------------------------------------------------------------------
template<int F16OUT>
__global__ __launch_bounds__(256) void gemm_h16(
    const _Float16* __restrict__ A, const _Float16* __restrict__ W,
    const float* __restrict__ bias, void* __restrict__ Cout)
{
  __shared__ __align__(16) _Float16 As[128 * 64];
  __shared__ __align__(16) _Float16 Bs[128 * 64];
  const int t = threadIdx.x;
  const int nwg = gridDim.x;
  int bid = blockIdx.x;
  bid = (bid & 7) * (nwg >> 3) + (bid >> 3);
  const int colb = bid % 6, rowb = bid / 6;
  const int row0 = rowb * 128, col0 = colb * 128;
  const int lane = t & 63, w = t >> 6;
  const int wr = w >> 1, wc = w & 1;
  const int l15 = lane & 15, l4 = lane >> 4;
  const int rl = lane >> 3;
  const int sl = lane & 7;

  f32x4 acc[4][4];
#pragma unroll
  for (int i = 0; i < 4; ++i)
#pragma unroll
    for (int j = 0; j < 4; ++j) acc[i][j] = (f32x4){0.f, 0.f, 0.f, 0.f};

  for (int kt = 0; kt < 12; ++kt) {
    const int k0 = kt * 64;
#pragma unroll
    for (int it = 0; it < 4; ++it) {
      const int rbase = it * 32 + w * 8;     // wave-uniform
      const int r = rbase + rl;
      const int sa = sl ^ (r & 7);           // pre-swizzled source granule
      __builtin_amdgcn_global_load_lds(
          (GLBv*)(A + (size_t)(row0 + r) * Cc + k0 + sa * 8),
          (LDSv*)&As[rbase * 64], 16, 0, 0);
      __builtin_amdgcn_global_load_lds(
          (GLBv*)(W + (size_t)(col0 + r) * Cc + k0 + sa * 8),
          (LDSv*)&Bs[rbase * 64], 16, 0, 0);
    }
    __syncthreads();
#pragma unroll
    for (int ks = 0; ks < 2; ++ks) {
      half8 af[4], bf[4];
#pragma unroll
      for (int mi = 0; mi < 4; ++mi) {
        const int r = wr * 64 + mi * 16 + l15;
        const int g = ks * 4 + l4;
        af[mi] = *(const half8*)&As[r * 64 + ((g ^ (r & 7)) * 8)];
      }
#pragma unroll
      for (int ni = 0; ni < 4; ++ni) {
        const int r = wc * 64 + ni * 16 + l15;
        const int g = ks * 4 + l4;
        bf[ni] = *(const half8*)&Bs[r * 64 + ((g ^ (r & 7)) * 8)];
      }
#pragma unroll
      for (int mi = 0; mi < 4; ++mi)
#pragma unroll
        for (int ni = 0; ni < 4; ++ni)
          acc[mi][ni] = __builtin_amdgcn_mfma_f32_16x16x32_f16(af[mi], bf[ni], acc[mi][ni], 0, 0, 0);
    }
    __syncthreads();
  }

#pragma unroll
  for (int ni = 0; ni < 4; ++ni) {
    const int col = col0 + wc * 64 + ni * 16 + l15;
    const float bcol = bias[col];
#pragma unroll
    for (int mi = 0; mi < 4; ++mi) {
      f32x4 v = acc[mi][ni];
      const int rbase = row0 + wr * 64 + mi * 16 + l4 * 4;
#pragma unroll
      for (int r = 0; r < 4; ++r) {
        if (F16OUT) {
          ((_Float16*)Cout)[(size_t)(rbase + r) * Cc + col] = (_Float16)(v[r] + bcol);
        } else {
          ((float*)Cout)[(size_t)(rbase + r) * Cc + col] = v[r] + bcol;
        }
      }
    }
  }
}

// ---------------------------------------------------------------------------
// Dual-output K+V GEMM (stacked Wk||Wv) — staging via global_load_lds x2.
// ---------------------------------------------------------------------------
__global__ __launch_bounds__(256) void gemm_h16_kv(
    const _Float16* __restrict__ A, const _Float16* __restrict__ Wkv,
    const float* __restrict__ bk, const float* __restrict__ bv,
    _Float16* __restrict__ K16, _Float16* __restrict__ V16)
{
  __shared__ __align__(16) _Float16 As[128 * 64];
  __shared__ __align__(16) _Float16 Bs[128 * 64];
  const int t = threadIdx.x;
  const int nwg = gridDim.x;
  int bid = blockIdx.x;
  bid = (bid & 7) * (nwg >> 3) + (bid >> 3);   // nwg = 2352, %8 == 0
  const int colb = bid % 12, rowb = bid / 12;
  const int row0 = rowb * 128, col0 = colb * 128;
  const int lane = t & 63, w = t >> 6;
  const int wr = w >> 1, wc = w & 1;
  const int l15 = lane & 15, l4 = lane >> 4;
  const int rl = lane >> 3;
  const int sl = lane & 7;

  _Float16* Cout = (colb < 6) ? K16 : V16;
  const float* bias = (colb < 6) ? bk : bv;
  const int cadj = (colb < 6) ? 0 : Cc;

  f32x4 acc[4][4];
#pragma unroll
  for (int i = 0; i < 4; ++i)
#pragma unroll
    for (int j = 0; j < 4; ++j) acc[i][j] = (f32x4){0.f, 0.f, 0.f, 0.f};

  for (int kt = 0; kt < 12; ++kt) {
    const int k0 = kt * 64;
#pragma unroll
    for (int it = 0; it < 4; ++it) {
      const int rbase = it * 32 + w * 8;
      const int r = rbase + rl;
      const int sa = sl ^ (r & 7);
      __builtin_amdgcn_global_load_lds(
          (GLBv*)(A + (size_t)(row0 + r) * Cc + k0 + sa * 8),
          (LDSv*)&As[rbase * 64], 16, 0, 0);
      __builtin_amdgcn_global_load_lds(
          (GLBv*)(Wkv + (size_t)(col0 + r) * Cc + k0 + sa * 8),
          (LDSv*)&Bs[rbase * 64], 16, 0, 0);
    }
    __syncthreads();
#pragma unroll
    for (int ks = 0; ks < 2; ++ks) {
      half8 af[4], bf[4];
#pragma unroll
      for (int mi = 0; mi < 4; ++mi) {
        const int r = wr * 64 + mi * 16 + l15;
        const int g = ks * 4 + l4;
        af[mi] = *(const half8*)&As[r * 64 + ((g ^ (r & 7)) * 8)];
      }
#pragma unroll
      for (int ni = 0; ni < 4; ++ni) {
        const int r = wc * 64 + ni * 16 + l15;
        const int g = ks * 4 + l4;
        bf[ni] = *(const half8*)&Bs[r * 64 + ((g ^ (r & 7)) * 8)];
      }
#pragma unroll
      for (int mi = 0; mi < 4; ++mi)
#pragma unroll
        for (int ni = 0; ni < 4; ++ni)
          acc[mi][ni] = __builtin_amdgcn_mfma_f32_16x16x32_f16(af[mi], bf[ni], acc[mi][ni], 0, 0, 0);
    }
    __syncthreads();
  }

#pragma unroll
  for (int ni = 0; ni < 4; ++ni) {
    const int col = col0 + wc * 64 + ni * 16 + l15;
    const float bcol = bias[col - cadj];
#pragma unroll
    for (int mi = 0; mi < 4; ++mi) {
      f32x4 v = acc[mi][ni];
      const int rbase = row0 + wr * 64 + mi * 16 + l4 * 4;
#pragma unroll
      for (int r = 0; r < 4; ++r)
        Cout[(size_t)(rbase + r) * Cc + (col - cadj)] = (_Float16)(v[r] + bcol);
    }
  }
}

// ---------------------------------------------------------------------------
// Offset network + bilinear sampling: TWO blocks (512 thr) per (b,g) —
// h-split 0..6 / 7..13 with 8-row halo staged (43 KB LDS -> serial rounds
// 13 -> 7 at same waves/SIMD).
// ---------------------------------------------------------------------------
__global__ __launch_bounds__(512, 4) void offset_sample(
    const _Float16* __restrict__ Q16, const float* __restrict__ hidden,
    const float* __restrict__ dw_w, const float* __restrict__ dw_b,
    const float* __restrict__ ln_w, const float* __restrict__ ln_b,
    const float* __restrict__ pw_w, _Float16* __restrict__ XS)
{
  __shared__ float Qs[8 * Ww * CgC];   // 43 KB (8 rows incl. halo)
  const int tid = threadIdx.x;
  const int g    = blockIdx.x & 7;
  const int half = blockIdx.x >> 3;    // 0: h 0..6, 1: h 7..13
  const int b = blockIdx.y;
  const int cl = tid & 31;
  const int grp = tid >> 5;            // 0..15
  const int hbase = half ? 6 : 0;      // staged rows hbase..hbase+7

  const size_t base = (size_t)b * Nn * Cc + g * CgC;
  // stage 8 rows (112 sites) of Q slice, fp16 -> fp32
  for (int i = tid; i < 8 * Ww * 12; i += 512) {
    const int n = i / 12, j = i - n * 12;          // n: local site 0..111
    const int gn = hbase * Ww + n;
    half8 hv = *(const half8*)(Q16 + base + (size_t)gn * Cc + j * 8);
#pragma unroll
    for (int e = 0; e < 8; ++e) Qs[n * CgC + j * 8 + e] = (float)hv[e];
  }

  float wdw[3][9], bdw[3], wln[3], bln[3], wp0[3], wp1[3];
#pragma unroll
  for (int k = 0; k < 3; ++k) {
    const int c = cl + k * 32;
#pragma unroll
    for (int t9 = 0; t9 < 9; ++t9) wdw[k][t9] = dw_w[c * 9 + t9];
    bdw[k] = dw_b[c];
    wln[k] = ln_w[c];
    bln[k] = ln_b[c];
    wp0[k] = pw_w[c];
    wp1[k] = pw_w[CgC + c];
  }
  __syncthreads();

  const float* hb0 = hidden + base;
  const int nsites = 7 * Ww;           // 98 per half

  for (int s0 = 0; s0 < nsites; s0 += 16) {
    const int slcl = s0 + grp;
    if (slcl < nsites) {
      const int site = half * nsites + slcl;
      const int h = site / Ww, w = site % Ww;

      float t[3];
#pragma unroll
      for (int k = 0; k < 3; ++k) t[k] = bdw[k];
#pragma unroll
      for (int ky = 0; ky < 3; ++ky) {
        const int hp = h + ky - 1;
        if (hp < 0 || hp > Hh - 1) continue;
#pragma unroll
        for (int kx = 0; kx < 3; ++kx) {
          const int wp = w + kx - 1;
          if (wp < 0 || wp > Ww - 1) continue;
          const float* row = &Qs[((hp - hbase) * Ww + wp) * CgC + cl];
#pragma unroll
          for (int k = 0; k < 3; ++k)
            t[k] = fmaf(row[k * 32], wdw[k][ky * 3 + kx], t[k]);
        }
      }

      float s = t[0] + t[1] + t[2];
#pragma unroll
      for (int off = 1; off <= 16; off <<= 1) s += __shfl_xor(s, off, 32);
      const float mu = s * (1.f / 96.f);
      float d2 = 0.f;
#pragma unroll
      for (int k = 0; k < 3; ++k) { const float d = t[k] - mu; d2 = fmaf(d, d, d2); }
#pragma unroll
      for (int off = 1; off <= 16; off <<= 1) d2 += __shfl_xor(d2, off, 32);
      const float rstd = rsqrtf(d2 * (1.f / 96.f) + 1e-5f);

      float p0 = 0.f, p1 = 0.f;
#pragma unroll
      for (int k = 0; k < 3; ++k) {
        const float tn = (t[k] - mu) * rstd * wln[k] + bln[k];
        const float a = 0.5f * tn * (1.f + erff(tn * 0.70710678118654752f));
        p0 = fmaf(a, wp0[k], p0);
        p1 = fmaf(a, wp1[k], p1);
      }
#pragma unroll
      for (int off = 1; off <= 16; off <<= 1) {
        p0 += __shfl_xor(p0, off, 32);
        p1 += __shfl_xor(p1, off, 32);
      }

      const float offy = tanhf(p0) * (1.f / 13.f);
      const float offx = tanhf(p1) * (1.f / 13.f);
      const float refy = (h + 0.5f) / 14.f * 2.f - 1.f;
      const float refx = (w + 0.5f) / 14.f * 2.f - 1.f;
      const float gx = ((offx + refx) + 1.f) * 0.5f * 13.f;
      const float gy = ((offy + refy) + 1.f) * 0.5f * 13.f;

      const float x0f = floorf(gx), y0f = floorf(gy);
      const int x0 = (int)x0f, y0 = (int)y0f;
      const float wx1 = gx - x0f, wx0 = 1.f - wx1;
      const float wy1 = gy - y0f, wy0 = 1.f - wy1;
      const bool vx0 = (x0 >= 0) & (x0 <= 13), vx1 = (x0 + 1 >= 0) & (x0 + 1 <= 13);
      const bool vy0 = (y0 >= 0) & (y0 <= 13), vy1 = (y0 + 1 >= 0) & (y0 + 1 <= 13);
      float acc[3] = {0.f, 0.f, 0.f};
#pragma unroll
      for (int k = 0; k < 3; ++k) {
        const int c = cl + k * 32;
        if (vx0 & vy0) acc[k] = fmaf(wx0 * wy0, hb0[(size_t)(y0 * Ww + x0) * Cc + c], acc[k]);
        if (vx1 & vy0) acc[k] = fmaf(wx1 * wy0, hb0[(size_t)(y0 * Ww + x0 + 1) * Cc + c], acc[k]);
        if (vx0 & vy1) acc[k] = fmaf(wx0 * wy1, hb0[(size_t)((y0 + 1) * Ww + x0) * Cc + c], acc[k]);
        if (vx1 & vy1) acc[k] = fmaf(wx1 * wy1, hb0[(size_t)((y0 + 1) * Ww + x0 + 1) * Cc + c], acc[k]);
      }
      _Float16* xp = XS + ((size_t)b * Nn + site) * Cc + g * CgC + cl;
#pragma unroll
      for (int k = 0; k < 3; ++k) xp[k * 32] = (_Float16)acc[k];
    }
  }
}

// ---------------------------------------------------------------------------
// Fused attention (unchanged): 8 waves per (b,h), LDS 69.9 KB, 2 blocks/CU.
// ---------------------------------------------------------------------------
__global__ __launch_bounds__(512, 4) void attn_fused(
    const _Float16* __restrict__ Qm, const _Float16* __restrict__ Km,
    const _Float16* __restrict__ Vm, float* __restrict__ attn,
    _Float16* __restrict__ OUT)
{
  __shared__ __align__(16) _Float16 Kt[208 * 72];
  __shared__ __align__(16) _Float16 Vt[64 * 232];
  __shared__ __align__(16) _Float16 Ps[8][16 * 40];
  const int tid = threadIdx.x;
  const int hh = blockIdx.x, b = blockIdx.y;
  const int lane = tid & 63, wv = tid >> 6;
  const int l15 = lane & 15, l4 = lane >> 4;

  const _Float16* Qbase = Qm + (size_t)b * Nn * Cc + hh * Dh;
  const _Float16* Kbase = Km + (size_t)b * Nn * Cc + hh * Dh;
  const _Float16* Vbase = Vm + (size_t)b * Nn * Cc + hh * Dh;

  {
    const int g = tid & 7;
    for (int n = tid >> 3; n < 208; n += 64) {
      half8 hv = {};
      if (n < Nn) hv = *(const half8*)(Kbase + (size_t)n * Cc + g * 8);
      *(half8*)&Kt[n * 72 + g * 8] = hv;
    }
  }
  {
    const int d0 = (tid & 15) * 4;
    for (int n = tid >> 4; n < Nn; n += 32) {
      half4 v = *(const half4*)(Vbase + (size_t)n * Cc + d0);
      Vt[(d0 + 0) * 232 + n] = v[0];
      Vt[(d0 + 1) * 232 + n] = v[1];
      Vt[(d0 + 2) * 232 + n] = v[2];
      Vt[(d0 + 3) * 232 + n] = v[3];
    }
    for (int e = tid; e < 64 * 36; e += 512) {
      int d = e / 36, n = Nn + e % 36;
      Vt[d * 232 + n] = (_Float16)0.f;
    }
  }
  __syncthreads();

  for (int mt = wv; mt < 13; mt += 8) {
    const int qrow = mt * 16 + l15;
    const _Float16* qp = Qbase + (size_t)(qrow < Nn ? qrow : (Nn - 1)) * Cc + l4 * 8;
    half8 aq0 = *(const half8*)qp;
    half8 aq1 = *(const half8*)(qp + 32);

    f32x4 accs[13];
#pragma unroll
    for (int nt = 0; nt < 13; ++nt) accs[nt] = (f32x4){0.f, 0.f, 0.f, 0.f};
#pragma unroll
    for (int nt = 0; nt < 13; ++nt) {
      const int rb = (nt * 16 + l15) * 72;
      half8 bk0 = *(const half8*)&Kt[rb + l4 * 8];
      half8 bk1 = *(const half8*)&Kt[rb + 32 + l4 * 8];
      accs[nt] = __builtin_amdgcn_mfma_f32_16x16x32_f16(aq0, bk0, accs[nt], 0, 0, 0);
      accs[nt] = __builtin_amdgcn_mfma_f32_16x16x32_f16(aq1, bk1, accs[nt], 0, 0, 0);
    }

    float rmax[4] = {-1e30f, -1e30f, -1e30f, -1e30f};
#pragma unroll
    for (int nt = 0; nt < 13; ++nt) {
#pragma unroll
      for (int r = 0; r < 4; ++r) {
        float s = accs[nt][r] * 0.125f;
        if (nt == 12 && l15 >= 4) s = -1e30f;
        accs[nt][r] = s;
        rmax[r] = fmaxf(rmax[r], s);
      }
    }
#pragma unroll
    for (int off = 1; off <= 8; off <<= 1)
#pragma unroll
      for (int r = 0; r < 4; ++r)
        rmax[r] = fmaxf(rmax[r], __shfl_xor(rmax[r], off, 64));

    float rsum[4] = {0.f, 0.f, 0.f, 0.f};
#pragma unroll
    for (int nt = 0; nt < 13; ++nt) {
#pragma unroll
      for (int r = 0; r < 4; ++r) {
        float p = __expf(accs[nt][r] - rmax[r]);
        accs[nt][r] = p;
        rsum[r] += p;
      }
    }
#pragma unroll
    for (int off = 1; off <= 8; off <<= 1)
#pragma unroll
      for (int r = 0; r < 4; ++r)
        rsum[r] += __shfl_xor(rsum[r], off, 64);
    float rinv[4];
#pragma unroll
    for (int r = 0; r < 4; ++r) rinv[r] = 1.f / rsum[r];

    float* ab = attn + (((size_t)b * NHh + hh) * Nn) * (size_t)Nn;
#pragma unroll
    for (int nt = 0; nt < 13; ++nt) {
      const int n = nt * 16 + l15;
#pragma unroll
      for (int r = 0; r < 4; ++r) {
        float pr = accs[nt][r] * rinv[r];
        accs[nt][r] = pr;
        const int m = mt * 16 + l4 * 4 + r;
        if (m < Nn && n < Nn) ab[(size_t)m * Nn + n] = pr;
      }
    }

    f32x4 acco[4];
#pragma unroll
    for (int dt = 0; dt < 4; ++dt) acco[dt] = (f32x4){0.f, 0.f, 0.f, 0.f};
#pragma unroll
    for (int nsl = 0; nsl < 7; ++nsl) {
#pragma unroll
      for (int h2 = 0; h2 < 2; ++h2) {
        const int nt = nsl * 2 + h2;
        if (nt < 13) {
#pragma unroll
          for (int r = 0; r < 4; ++r)
            Ps[wv][(l4 * 4 + r) * 40 + h2 * 16 + l15] = (_Float16)accs[nt][r];
        } else {
#pragma unroll
          for (int r = 0; r < 4; ++r)
            Ps[wv][(l4 * 4 + r) * 40 + h2 * 16 + l15] = (_Float16)0.f;
        }
      }
      half8 ap = *(const half8*)&Ps[wv][l15 * 40 + l4 * 8];
#pragma unroll
      for (int dt = 0; dt < 4; ++dt) {
        half8 bv = *(const half8*)&Vt[(dt * 16 + l15) * 232 + nsl * 32 + l4 * 8];
        acco[dt] = __builtin_amdgcn_mfma_f32_16x16x32_f16(ap, bv, acco[dt], 0, 0, 0);
      }
    }
#pragma unroll
    for (int dt = 0; dt < 4; ++dt) {
#pragma unroll
      for (int r = 0; r < 4; ++r) {
        const int m = mt * 16 + l4 * 4 + r;
        if (m < Nn)
          OUT[((size_t)b * Nn + m) * Cc + hh * Dh + dt * 16 + l15] = (_Float16)acco[dt][r];
      }
    }
  }
}

// ---------------------------------------------------------------------------
extern "C" void kernel_launch(void* const* d_in, const int* in_sizes, int n_in,
                              void* d_out, int out_size, void* d_ws, size_t ws_size,
                              hipStream_t stream) {
  const float* hidden = (const float*)d_in[0];
  const float* Wq = (const float*)d_in[1];
  const float* bq = (const float*)d_in[2];
  const float* dw_w = (const float*)d_in[3];
  const float* dw_b = (const float*)d_in[4];
  const float* ln_w = (const float*)d_in[5];
  const float* ln_b = (const float*)d_in[6];
  const float* pw_w = (const float*)d_in[7];
  const float* Wk = (const float*)d_in[8];
  const float* bk = (const float*)d_in[9];
  const float* Wv = (const float*)d_in[10];
  const float* bv = (const float*)d_in[11];
  const float* Wp = (const float*)d_in[12];
  const float* bp = (const float*)d_in[13];
  const float* Wo = (const float*)d_in[14];
  const float* bo = (const float*)d_in[15];

  const size_t SZ = (size_t)Bsz * Nn * Cc;      // 19,267,584
  float* yout = (float*)d_out;                  // (B,N,C) fp32
  float* attn = yout + SZ;                      // (B,12,196,196) fp32 probs

  _Float16* Q16   = (_Float16*)d_ws;            // fp16 workspace buffers
  _Float16* XS16  = Q16   + SZ;
  _Float16* K16   = XS16  + SZ;
  _Float16* V16   = K16   + SZ;
  _Float16* OUT16 = V16   + SZ;
  _Float16* W16   = OUT16 + SZ;                 // 5 x 768 x 768 (Wq,Wk,Wv,Wp,Wo)
  _Float16* Wf16  = W16   + 5 * (size_t)Cc * Cc;       // fused Wo@Wp
  float*    bf    = (float*)(Wf16 + (size_t)Cc * Cc);  // fused bias (768)

  const int gemm_blocks = (ROWS / 128) * (Cc / 128);  // 1176
  const int kv_blocks   = (ROWS / 128) * 12;          // 2352

  // 0. one-shot conversions + fused proj*out weight/bias
  cvt_w5<<<(5 * Cc * Cc / 8 + 255) / 256, 256, 0, stream>>>(Wq, Wk, Wv, Wp, Wo, W16);
  gemm_ww<<<36, 256, 0, stream>>>(W16 + 4 * (size_t)Cc * Cc, W16 + 3 * (size_t)Cc * Cc, Wf16);
  fuse_bias<<<Cc, 256, 0, stream>>>(Wo, bp, bo, bf);

  // 1. Q16 = hidden @ Wq^T + bq
  gemm_f32a<<<gemm_blocks, 256, 0, stream>>>(hidden, W16 + 0 * (size_t)Cc * Cc, bq, Q16);
  // 2. offset network + bilinear sampling -> XS16  (2 blocks per (b,g))
  offset_sample<<<dim3(Gg * 2, Bsz), 512, 0, stream>>>(Q16, hidden, dw_w, dw_b, ln_w, ln_b, pw_w, XS16);
  // 3. K16,V16 in one dispatch (stacked Wk||Wv, A staged once)
  gemm_h16_kv<<<kv_blocks, 256, 0, stream>>>(XS16, W16 + 1 * (size_t)Cc * Cc, bk, bv, K16, V16);
  // 4. fused scores+softmax+PV -> attn (fp32 probs) + OUT16
  attn_fused<<<dim3(NHh, Bsz), 512, 0, stream>>>(Q16, K16, V16, attn, OUT16);
  // 5. y = OUT16 @ (Wo@Wp)^T + (Wo@bp + bo) -> d_out (fp32)
  gemm_h16<0><<<gemm_blocks, 256, 0, stream>>>(OUT16, Wf16, bf, yout);
}